// Round 17
// baseline (198.385 us; speedup 1.0000x reference)
//
#include <hip/hip_runtime.h>
#include <math.h>

using bf16   = __bf16;
using bf16x8 = __attribute__((ext_vector_type(8))) __bf16;
using bf16x4 = __attribute__((ext_vector_type(4))) __bf16;
using f32x4  = __attribute__((ext_vector_type(4))) float;

constexpr int S_   = 2048;
constexpr int D_   = 768;
constexpr int DFF_ = 3072;
constexpr int M_   = 4096;   // B*S
constexpr int BH_  = 24;     // B*H

__device__ __forceinline__ f32x4 mfma16(bf16x8 a, bf16x8 b, f32x4 c) {
    return __builtin_amdgcn_mfma_f32_16x16x32_bf16(a, b, c, 0, 0, 0);
}

__device__ __forceinline__ void gload16(const bf16* g, bf16* l) {
    __builtin_amdgcn_global_load_lds(
        (const __attribute__((address_space(1))) void*)g,
        (__attribute__((address_space(3))) void*)l, 16, 0, 0);
}

template<int N> __device__ __forceinline__ void wait_vmcnt() {
    if constexpr (N == 0)      asm volatile("s_waitcnt vmcnt(0)" ::: "memory");
    else if constexpr (N == 4) asm volatile("s_waitcnt vmcnt(4)" ::: "memory");
    else if constexpr (N == 6) asm volatile("s_waitcnt vmcnt(6)" ::: "memory");
    else if constexpr (N == 8) asm volatile("s_waitcnt vmcnt(8)" ::: "memory");
    else static_assert(N == 0, "unsupported vmcnt");
}
__device__ __forceinline__ void wait_lgkm0() {
    asm volatile("s_waitcnt lgkmcnt(0)" ::: "memory");
}

__device__ __forceinline__ int xcd_swz(int orig, int nwg) {
    return (orig & 7) * (nwg >> 3) + (orig >> 3);
}

__device__ __forceinline__ float gelu_f(float v) {
    float y = 1.5957691f * (v + 0.044715f * v * v * v);
    return v / (1.0f + __expf(-y));
}

__global__ __launch_bounds__(256)
void pack_x_kernel(const float* __restrict__ x, bf16* __restrict__ xb) {
    const int i = blockIdx.x * 256 + threadIdx.x;
    float4 v = ((const float4*)x)[i];
    bf16x4 o;
    o[0] = (bf16)v.x; o[1] = (bf16)v.y; o[2] = (bf16)v.z; o[3] = (bf16)v.w;
    ((bf16x4*)xb)[i] = o;
}

__global__ __launch_bounds__(256)
void merge_ao_kernel(const bf16* __restrict__ a, const bf16* __restrict__ b,
                     bf16* __restrict__ o) {
    const long i = ((long)blockIdx.x * 256 + threadIdx.x) * 8;
    bf16x8 va = *(const bf16x8*)&a[i];
    bf16x8 vb = *(const bf16x8*)&b[i];
    bf16x8 vo;
#pragma unroll
    for (int j = 0; j < 8; j++) vo[j] = (bf16)((float)va[j] + (float)vb[j]);
    *(bf16x8*)&o[i] = vo;
}

// ---------------------------------------------------------------------------
// merge split-K GEMM partials (+bias +residual), then LayerNorm over D=768.
// ---------------------------------------------------------------------------
template<bool FIRST>
__global__ __launch_bounds__(256)
void merge_ln_kernel(const bf16* __restrict__ pp, const float* __restrict__ bias,
                     const float* __restrict__ residf, const bf16* __restrict__ residb,
                     const float* __restrict__ gamma, const float* __restrict__ beta,
                     float* __restrict__ outf, bf16* __restrict__ outb) {
    __shared__ float sa[4], sb[4];
    const int row = blockIdx.x, t = threadIdx.x;
    const bf16* p0 = pp + (long)row * 768;
    const bf16* p1 = pp + (long)M_ * 768 + (long)row * 768;
    float v[3];
#pragma unroll
    for (int i = 0; i < 3; i++) {
        const int c = t + i * 256;
        float y = (float)p0[c] + (float)p1[c] + bias[c];
        if (FIRST) y += residf[(long)row * 768 + c];
        else       y += (float)residb[(long)row * 768 + c];
        v[i] = y;
    }
    float s  = v[0] + v[1] + v[2];
    float ss = v[0] * v[0] + v[1] * v[1] + v[2] * v[2];
#pragma unroll
    for (int o = 32; o; o >>= 1) { s += __shfl_xor(s, o); ss += __shfl_xor(ss, o); }
    if ((t & 63) == 0) { sa[t >> 6] = s; sb[t >> 6] = ss; }
    __syncthreads();
    s  = sa[0] + sa[1] + sa[2] + sa[3];
    ss = sb[0] + sb[1] + sb[2] + sb[3];
    const float mu   = s * (1.0f / 768.0f);
    const float var  = ss * (1.0f / 768.0f) - mu * mu;
    const float rstd = rsqrtf(var + 1e-5f);
#pragma unroll
    for (int i = 0; i < 3; i++) {
        const int c = t + i * 256;
        const float ov = (v[i] - mu) * rstd * gamma[c] + beta[c];
        if (FIRST) outb[(long)row * 768 + c] = (bf16)ov;
        else       outf[(long)row * 768 + c] = ov;
    }
}

__global__ __launch_bounds__(256)
void wt_all_kernel(const float* __restrict__ Wq, const float* __restrict__ Wk,
                   const float* __restrict__ Wv, const float* __restrict__ Wo,
                   const float* __restrict__ W1, const float* __restrict__ W2,
                   bf16* __restrict__ Wqkvt, bf16* __restrict__ Wot,
                   bf16* __restrict__ W1t, bf16* __restrict__ W2t) {
    int bid = blockIdx.x;
    const float* in; bf16* out; int K, N, t;
    if (bid < 576) {
        int m = bid / 144; t = bid % 144; K = 768; N = 768;
        in  = (m == 0) ? Wq : (m == 1) ? Wk : (m == 2) ? Wv : Wo;
        out = (m == 3) ? Wot : Wqkvt + (size_t)m * 768 * 768;
    } else if (bid < 1152) {
        t = bid - 576; K = 768; N = 3072; in = W1; out = W1t;
    } else {
        t = bid - 1152; K = 3072; N = 768; in = W2; out = W2t;
    }
    const int ntx = N / 64;
    const int n0 = (t % ntx) * 64, k0 = (t / ntx) * 64;

    __shared__ __align__(16) bf16 T[64][72];
    const int tt = threadIdx.x;
    const int r  = tt >> 2, c0 = (tt & 3) * 16;
    const float* src = in + (size_t)(k0 + r) * N + n0 + c0;
#pragma unroll
    for (int j = 0; j < 16; j += 4) {
        float4 v = *(const float4*)(src + j);
        T[r][c0 + j + 0] = (bf16)v.x;
        T[r][c0 + j + 1] = (bf16)v.y;
        T[r][c0 + j + 2] = (bf16)v.z;
        T[r][c0 + j + 3] = (bf16)v.w;
    }
    __syncthreads();
    bf16x8 o0, o1;
#pragma unroll
    for (int j = 0; j < 8; j++) { o0[j] = T[c0 + j][r]; o1[j] = T[c0 + 8 + j][r]; }
    bf16* dst = out + (size_t)(n0 + r) * K + k0 + c0;
    *(bf16x8*)(dst)     = o0;
    *(bf16x8*)(dst + 8) = o1;
}

// ---------------------------------------------------------------------------
// GEMM: C = A[M,K] @ Bt[N,K]^T (unchanged from R15/R16).
// ---------------------------------------------------------------------------
template<int EPI, int K, int BM, int BN, int WR, int WC, int KSPLIT>
__global__ __launch_bounds__(256)
void gemm_bt(const bf16* __restrict__ A, const bf16* __restrict__ Bt,
             const float* __restrict__ bias0, const float* __restrict__ bias1,
             const float* __restrict__ bias2,
             bf16* __restrict__ outb,
             bf16* __restrict__ qo, bf16* __restrict__ ko, bf16* __restrict__ vo) {
    constexpr int MR  = BM / WR / 16;
    constexpr int NR  = BN / WC / 16;
    constexpr int GA  = BM / 32;
    constexpr int GB  = BN / 32;
    constexpr int NPT = GA + GB;
    constexpr int KS  = K / KSPLIT;
    constexpr int NCOL = (EPI == 0) ? 2304 : (EPI == 2) ? 3072 : 768;
    constexpr int NBX  = NCOL / BN;
    __shared__ __align__(16) bf16 Al[2 * BM * 64];
    __shared__ __align__(16) bf16 Bl[2 * BN * 64];
    const int tid  = threadIdx.x;
    const int lane = tid & 63, w = tid >> 6;
    const int wr = w / WC, wc = w % WC;
    const int wg = xcd_swz(blockIdx.x, gridDim.x);
    const int ks = wg % KSPLIT;
    const int tt = wg / KSPLIT;
    const int m0 = (tt / NBX) * BM, n0 = (tt % NBX) * BN;
    const int kb = ks * KS;
    const int g = lane >> 4, q = lane & 15;
    const int srow = lane >> 3;
    const int schunk = (((lane & 7) ^ ((lane >> 3) & 7))) * 8;

    f32x4 acc[MR][NR] = {};

    const bf16* gaA = A  + (long)(m0 + w * (BM / 4) + srow) * K + kb + schunk;
    const bf16* gaB = Bt + (long)(n0 + w * (BN / 4) + srow) * K + kb + schunk;

    auto stage = [&](int buf, int kt) {
#pragma unroll
        for (int i = 0; i < GA; i++)
            gload16(gaA + kt + (long)i * 8 * K,
                    &Al[buf * BM * 64 + (w * (BM / 4) + i * 8) * 64]);
#pragma unroll
        for (int i = 0; i < GB; i++)
            gload16(gaB + kt + (long)i * 8 * K,
                    &Bl[buf * BN * 64 + (w * (BN / 4) + i * 8) * 64]);
    };
    auto compute = [&](int buf) {
#pragma unroll
        for (int c = 0; c < 2; c++) {
            const int rch = ((c * 4 + g) ^ (q & 7)) * 8;
            bf16x8 af[MR], bfr[NR];
#pragma unroll
            for (int i = 0; i < MR; i++)
                af[i] = *(const bf16x8*)
                    &Al[buf * BM * 64 + (wr * (BM / WR) + i * 16 + q) * 64 + rch];
#pragma unroll
            for (int i = 0; i < NR; i++)
                bfr[i] = *(const bf16x8*)
                    &Bl[buf * BN * 64 + (wc * (BN / WC) + i * 16 + q) * 64 + rch];
#pragma unroll
            for (int mi = 0; mi < MR; mi++)
#pragma unroll
                for (int ni = 0; ni < NR; ni++)
                    acc[mi][ni] = mfma16(af[mi], bfr[ni], acc[mi][ni]);
        }
    };

    stage(0, 0);
    stage(1, 64);
    int cur = 0;
    for (int kt = 0; kt < KS - 64; kt += 64) {
        wait_vmcnt<NPT>();
        __builtin_amdgcn_s_barrier();
        compute(cur);
        wait_lgkm0();
        __builtin_amdgcn_s_barrier();
        if (kt + 128 < KS) stage(cur, kt + 128);
        cur ^= 1;
    }
    wait_vmcnt<0>();
    __builtin_amdgcn_s_barrier();
    compute(cur);

#pragma unroll
    for (int mi = 0; mi < MR; mi++) {
        if (EPI == 0) {
            const int col0  = n0 + wc * 64;
            const int which = (col0 >= 1536) ? 2 : (col0 >= 768 ? 1 : 0);
            const int row0  = m0 + wr * (BM / WR) + mi * 16 + g * 4;
            float val[NR][4];
#pragma unroll
            for (int ni = 0; ni < NR; ni++) {
                const int dd = col0 + ni * 16 + q - which * 768;
                const float bias = (which == 0 ? bias0 : which == 1 ? bias1 : bias2)[dd];
#pragma unroll
                for (int r = 0; r < 4; r++) val[ni][r] = acc[mi][ni][r] + bias;
            }
            if (which <= 1) {
#pragma unroll
                for (int r = 0; r < 4; r++) {
                    float ss = val[0][r] * val[0][r];
#pragma unroll
                    for (int ni = 1; ni < NR; ni++) ss += val[ni][r] * val[ni][r];
                    ss += __shfl_xor(ss, 1);
                    ss += __shfl_xor(ss, 2);
                    ss += __shfl_xor(ss, 4);
                    ss += __shfl_xor(ss, 8);
                    const float rn = 1.0f / fmaxf(sqrtf(ss), 1e-12f);
#pragma unroll
                    for (int ni = 0; ni < NR; ni++) val[ni][r] *= rn;
                }
            }
            const int dd0 = col0 - which * 768;
            const int hh  = dd0 >> 6;
            const long bh = (long)(row0 >> 11) * 12 + hh;
#pragma unroll
            for (int ni = 0; ni < NR; ni++) {
                const int dk = ni * 16 + q;
                if (which == 2) {
                    bf16x4 pv;
#pragma unroll
                    for (int r = 0; r < 4; r++) pv[r] = (bf16)val[ni][r];
                    *(bf16x4*)&vo[(bh * 64 + dk) * 2048 + (row0 & 2047)] = pv;
                } else {
                    bf16* dst = (which == 0) ? qo : ko;
#pragma unroll
                    for (int r = 0; r < 4; r++)
                        dst[(bh * 2048 + ((row0 + r) & 2047)) * 64 + dk] = (bf16)val[ni][r];
                }
            }
        } else if (EPI == 2) {
#pragma unroll
            for (int ni = 0; ni < NR; ni++) {
                const int col  = n0 + wc * (BN / WC) + ni * 16 + q;
                const int row0 = m0 + wr * (BM / WR) + mi * 16 + g * 4;
                const float bias = bias0[col];
#pragma unroll
                for (int r = 0; r < 4; r++) {
                    const float v = acc[mi][ni][r] + bias;
                    outb[(long)(row0 + r) * 3072 + col] = (bf16)gelu_f(v);
                }
            }
        } else {  // EPI 1/3 with KSPLIT: raw bf16 partial
#pragma unroll
            for (int ni = 0; ni < NR; ni++) {
                const int col  = n0 + wc * (BN / WC) + ni * 16 + q;
                const int row0 = m0 + wr * (BM / WR) + mi * 16 + g * 4;
#pragma unroll
                for (int r = 0; r < 4; r++)
                    outb[(long)ks * M_ * 768 + (long)(row0 + r) * 768 + col] =
                        (bf16)acc[mi][ni][r];
            }
        }
    }
}

// ---------------------------------------------------------------------------
// Attention split-K over keys (PV linear, no softmax), skewed qk||pv pipe.
// LDS: unpadded 64-wide rows with within-row XOR chunk swizzle on K/V/P
// (write chunk = (lane&7)^(srow&7); read chunk = logicalchunk^(row&7);
// row&7 == q15&7 since block rows are multiples of 16) -> conflict-free AND
// exactly 40960 B -> 4 blocks/CU (was 46080 B / 3 blocks).
// Grid 768 = 2 kv-halves x 16 qblocks x 24 bh.
// ---------------------------------------------------------------------------
__global__ __launch_bounds__(256, 4)
void attn_kernel(const bf16* __restrict__ Qn, const bf16* __restrict__ Kn,
                 const bf16* __restrict__ Vt, bf16* __restrict__ AOp) {
    const int wg  = xcd_swz(blockIdx.x, gridDim.x);
    const int bh  = wg >> 5;
    const int rem = wg & 31;
    const int kvhalf = rem >> 4;
    const int qblk   = rem & 15;
    const int tid = threadIdx.x, lane = tid & 63, w = tid >> 6;
    const int g = lane >> 4, q15 = lane & 15;
    const int qbase = qblk * 128 + w * 32;
    const int kv0   = kvhalf * 1024;
    constexpr int NT = 16;

    __shared__ __align__(16) bf16 Kl[2][64][64];
    __shared__ __align__(16) bf16 Vl[2][64][64];
    __shared__ __align__(16) bf16 Pl[4][16][64];
    bf16 (*Pw)[64] = Pl[w];

    const bf16* Qp = Qn + (long)bh * S_ * 64;
    const bf16* Kp = Kn + (long)bh * S_ * 64 + (long)kv0 * 64;
    const bf16* Vp = Vt + (long)bh * 64 * S_ + kv0;
    bf16* AOo = AOp + (long)kvhalf * M_ * D_;

    const int srow = tid >> 3, scol = (tid & 7) * 8;
    // swizzled LDS column for staging writes: chunk (lane&7) ^ (srow&7)
    const int ssw  = (((lane & 7) ^ ((lane >> 3) & 7))) * 8;
    const int q7   = q15 & 7;

    bf16x8 qf00 = *(const bf16x8*)&Qp[(long)(qbase + q15) * 64 + g * 8];
    bf16x8 qf01 = *(const bf16x8*)&Qp[(long)(qbase + q15) * 64 + 32 + g * 8];
    bf16x8 qf10 = *(const bf16x8*)&Qp[(long)(qbase + 16 + q15) * 64 + g * 8];
    bf16x8 qf11 = *(const bf16x8*)&Qp[(long)(qbase + 16 + q15) * 64 + 32 + g * 8];

    f32x4 o0[4] = {}, o1[4] = {};
    bf16x8 kf[4][2], vf[4][2];
    bf16x8 aK0, aK1, aV0, aV1, bK0, bK1, bV0, bV1;

    auto gloadA = [&](int kt) {
        aK0 = *(const bf16x8*)&Kp[(long)(kt + srow) * 64 + scol];
        aK1 = *(const bf16x8*)&Kp[(long)(kt + 32 + srow) * 64 + scol];
        aV0 = *(const bf16x8*)&Vp[(long)srow * S_ + kt + scol];
        aV1 = *(const bf16x8*)&Vp[(long)(32 + srow) * S_ + kt + scol];
    };
    auto gloadB = [&](int kt) {
        bK0 = *(const bf16x8*)&Kp[(long)(kt + srow) * 64 + scol];
        bK1 = *(const bf16x8*)&Kp[(long)(kt + 32 + srow) * 64 + scol];
        bV0 = *(const bf16x8*)&Vp[(long)srow * S_ + kt + scol];
        bV1 = *(const bf16x8*)&Vp[(long)(32 + srow) * S_ + kt + scol];
    };
    // NOTE: source col is UNswizzled (scol); dest col is swizzled (ssw).
    // Read side undoes it with chunk^(row&7). Both sides consistent (rule 21).
    auto stageA = [&](int buf) {
        *(bf16x8*)&Kl[buf][srow][ssw]      = aK0;
        *(bf16x8*)&Kl[buf][32 + srow][ssw] = aK1;
        *(bf16x8*)&Vl[buf][srow][ssw]      = aV0;
        *(bf16x8*)&Vl[buf][32 + srow][ssw] = aV1;
    };
    auto stageB = [&](int buf) {
        *(bf16x8*)&Kl[buf][srow][ssw]      = bK0;
        *(bf16x8*)&Kl[buf][32 + srow][ssw] = bK1;
        *(bf16x8*)&Vl[buf][srow][ssw]      = bV0;
        *(bf16x8*)&Vl[buf][32 + srow][ssw] = bV1;
    };
    // wait: the staged data at dest chunk c_sw holds SOURCE chunk (lane&7).
    // dest chunk = (lane&7)^(srow&7)  <=>  source chunk s = c_sw^(row&7).
    // Reader wanting logical chunk c reads dest chunk c^(row&7). ✓

    auto loadKf = [&](int cur) {
#pragma unroll
        for (int ni = 0; ni < 4; ni++)
#pragma unroll
            for (int c = 0; c < 2; c++)
                kf[ni][c] = *(const bf16x8*)
                    &Kl[cur][ni * 16 + q15][(((c * 4 + g) ^ q7)) * 8];
    };
    auto loadVf = [&](int cur) {
#pragma unroll
        for (int ni = 0; ni < 4; ni++)
#pragma unroll
            for (int c = 0; c < 2; c++)
                vf[ni][c] = *(const bf16x8*)
                    &Vl[cur][ni * 16 + q15][(((c * 4 + g) ^ q7)) * 8];
    };
    auto qk = [&](bf16x8 qa, bf16x8 qb) {
        f32x4 s[4];
#pragma unroll
        for (int ni = 0; ni < 4; ni++) {
            s[ni] = mfma16(kf[ni][0], qa, f32x4{0.f, 0.f, 0.f, 0.f});
            s[ni] = mfma16(kf[ni][1], qb, s[ni]);
        }
#pragma unroll
        for (int ni = 0; ni < 4; ni++) {
            bf16x4 p4;
#pragma unroll
            for (int r = 0; r < 4; r++) { float v = s[ni][r]; p4[r] = (bf16)(v * v); }
            // element k0 = ni*16 + g*4 -> chunk = ni*2 + (g>>1), offs (g&1)*4
            const int ch = (ni * 2 + (g >> 1)) ^ q7;
            *(bf16x4*)&Pw[q15][ch * 8 + (g & 1) * 4] = p4;
        }
    };
    auto pv = [&](f32x4 (&o)[4]) {
        bf16x8 pf0 = *(const bf16x8*)&Pw[q15][((g ^ q7)) * 8];
        bf16x8 pf1 = *(const bf16x8*)&Pw[q15][(((4 + g) ^ q7)) * 8];
#pragma unroll
        for (int ni = 0; ni < 4; ni++) {
            o[ni] = mfma16(pf0, vf[ni][0], o[ni]);
            o[ni] = mfma16(pf1, vf[ni][1], o[ni]);
        }
    };

    // prologue: tile 0 (slot 0), tile1 regs in B, tile2 gload into A
    gloadA(0);
    stageA(0);
    gloadB(64);
    wait_lgkm0(); __builtin_amdgcn_s_barrier();
    stageB(1);
    gloadA(2 * 64);
    loadKf(0); qk(qf00, qf01);
    loadVf(0); pv(o0);
    qk(qf10, qf11);

    for (int t = 1; t <= NT - 3; t += 2) {
        pv(o1);
        wait_lgkm0(); __builtin_amdgcn_s_barrier();
        stageA(0);
        gloadB((t + 2) * 64);
        loadKf(1); qk(qf00, qf01);
        loadVf(1); pv(o0);
        qk(qf10, qf11);

        pv(o1);
        wait_lgkm0(); __builtin_amdgcn_s_barrier();
        stageB(1);
        if (t + 3 < NT) gloadA((t + 3) * 64);
        loadKf(0); qk(qf00, qf01);
        loadVf(0); pv(o0);
        qk(qf10, qf11);
    }
    pv(o1);
    wait_lgkm0(); __builtin_amdgcn_s_barrier();
    loadKf(1); qk(qf00, qf01);
    loadVf(1); pv(o0);
    qk(qf10, qf11);
    pv(o1);

    const int b = bh / 12, h = bh % 12;
#pragma unroll
    for (int ni = 0; ni < 4; ni++)
#pragma unroll
        for (int r = 0; r < 4; r++) {
            const int s0r = qbase + g * 4 + r;
            AOo[((long)b * S_ + s0r) * D_ + h * 64 + ni * 16 + q15] = (bf16)o0[ni][r];
            const int s1r = qbase + 16 + g * 4 + r;
            AOo[((long)b * S_ + s1r) * D_ + h * 64 + ni * 16 + q15] = (bf16)o1[ni][r];
        }
}

extern "C" void kernel_launch(void* const* d_in, const int* in_sizes, int n_in,
                              void* d_out, int out_size, void* d_ws, size_t ws_size,
                              hipStream_t stream) {
    const float* x     = (const float*)d_in[0];
    const float* Wq    = (const float*)d_in[1];
    const float* bq    = (const float*)d_in[2];
    const float* Wk    = (const float*)d_in[3];
    const float* bk    = (const float*)d_in[4];
    const float* Wv    = (const float*)d_in[5];
    const float* bv    = (const float*)d_in[6];
    const float* Wo    = (const float*)d_in[7];
    const float* bo    = (const float*)d_in[8];
    const float* W1    = (const float*)d_in[9];
    const float* b1    = (const float*)d_in[10];
    const float* W2    = (const float*)d_in[11];
    const float* b2    = (const float*)d_in[12];
    const float* gamma = (const float*)d_in[13];
    const float* beta  = (const float*)d_in[14];

    char* p = (char*)d_ws;
    auto alloc = [&](size_t bytes) -> void* {
        void* r = p;
        p += (bytes + 255) & ~(size_t)255;
        return r;
    };
    bf16*  Xb    = (bf16*)alloc((size_t)M_ * D_ * 2);
    bf16*  Wqkvt = (bf16*)alloc((size_t)2304 * 768 * 2);
    bf16*  Wot   = (bf16*)alloc((size_t)768 * 768 * 2);
    bf16*  W1t   = (bf16*)alloc((size_t)3072 * 768 * 2);
    bf16*  W2t   = (bf16*)alloc((size_t)768 * 3072 * 2);
    bf16*  Qh    = (bf16*)alloc((size_t)BH_ * S_ * 64 * 2);
    bf16*  Kh    = (bf16*)alloc((size_t)BH_ * S_ * 64 * 2);
    bf16*  Vt    = (bf16*)alloc((size_t)BH_ * S_ * 64 * 2);
    bf16*  AOp   = (bf16*)alloc((size_t)2 * M_ * D_ * 2);  // attn partials
    bf16*  AO    = (bf16*)alloc((size_t)M_ * D_ * 2);
    bf16*  pp    = (bf16*)alloc((size_t)2 * M_ * 768 * 2); // GEMM K-split partials
    bf16*  x1b   = (bf16*)alloc((size_t)M_ * D_ * 2);
    bf16*  hbuf  = (bf16*)alloc((size_t)M_ * DFF_ * 2);

    pack_x_kernel<<<(M_ * D_) / 1024, 256, 0, stream>>>(x, Xb);
    wt_all_kernel<<<1728, 256, 0, stream>>>(Wq, Wk, Wv, Wo, W1, W2,
                                            Wqkvt, Wot, W1t, W2t);

    // QKV: 64x128 tiles -> 1152 blocks (48KB LDS, 3/CU)
    gemm_bt<0, 768, 64, 128, 2, 2, 1><<<64 * 18, 256, 0, stream>>>(
        Xb, Wqkvt, bq, bk, bv, nullptr, Qh, Kh, Vt);

    // attention: 768 blocks, split-K over keys (4 blocks/CU now), then merge
    attn_kernel<<<2 * 16 * BH_, 256, 0, stream>>>(Qh, Kh, Vt, AOp);
    merge_ao_kernel<<<(M_ * D_) / 2048, 256, 0, stream>>>(
        AOp, AOp + (size_t)M_ * D_, AO);

    // Wo: 64x128 tiles + K-split x2 -> 768 blocks; merge + bias + resid + LN1
    gemm_bt<1, 768, 64, 128, 2, 2, 2><<<64 * 6 * 2, 256, 0, stream>>>(
        AO, Wot, nullptr, nullptr, nullptr, pp, nullptr, nullptr, nullptr);
    merge_ln_kernel<true><<<M_, 256, 0, stream>>>(
        pp, bo, x, nullptr, gamma, beta, nullptr, x1b);

    // FFN1: 64x128 tiles -> 1536 blocks
    gemm_bt<2, 768, 64, 128, 2, 2, 1><<<64 * 24, 256, 0, stream>>>(
        x1b, W1t, b1, nullptr, nullptr, hbuf, nullptr, nullptr, nullptr);

    // FFN2: 64x128 tiles + K-split x2 -> 768 blocks; merge + bias + resid + LN2
    gemm_bt<3, 3072, 64, 128, 2, 2, 2><<<64 * 6 * 2, 256, 0, stream>>>(
        hbuf, W2t, nullptr, nullptr, nullptr, pp, nullptr, nullptr, nullptr);
    merge_ln_kernel<false><<<M_, 256, 0, stream>>>(
        pp, b2, nullptr, x1b, gamma, beta, (float*)d_out, nullptr);
}

// Round 18
// 155.927 us; speedup vs baseline: 1.2723x; 1.2723x over previous
//
#include <hip/hip_runtime.h>
#include <math.h>

using bf16   = __bf16;
using bf16x8 = __attribute__((ext_vector_type(8))) __bf16;
using bf16x4 = __attribute__((ext_vector_type(4))) __bf16;
using f32x4  = __attribute__((ext_vector_type(4))) float;

constexpr int S_   = 2048;
constexpr int D_   = 768;
constexpr int DFF_ = 3072;
constexpr int M_   = 4096;   // B*S
constexpr int BH_  = 24;     // B*H

__device__ __forceinline__ f32x4 mfma16(bf16x8 a, bf16x8 b, f32x4 c) {
    return __builtin_amdgcn_mfma_f32_16x16x32_bf16(a, b, c, 0, 0, 0);
}

__device__ __forceinline__ void gload16(const bf16* g, bf16* l) {
    __builtin_amdgcn_global_load_lds(
        (const __attribute__((address_space(1))) void*)g,
        (__attribute__((address_space(3))) void*)l, 16, 0, 0);
}

template<int N> __device__ __forceinline__ void wait_vmcnt() {
    if constexpr (N == 0)      asm volatile("s_waitcnt vmcnt(0)" ::: "memory");
    else if constexpr (N == 4) asm volatile("s_waitcnt vmcnt(4)" ::: "memory");
    else if constexpr (N == 6) asm volatile("s_waitcnt vmcnt(6)" ::: "memory");
    else if constexpr (N == 8) asm volatile("s_waitcnt vmcnt(8)" ::: "memory");
    else static_assert(N == 0, "unsupported vmcnt");
}
__device__ __forceinline__ void wait_lgkm0() {
    asm volatile("s_waitcnt lgkmcnt(0)" ::: "memory");
}

__device__ __forceinline__ int xcd_swz(int orig, int nwg) {
    return (orig & 7) * (nwg >> 3) + (orig >> 3);
}

__device__ __forceinline__ float gelu_f(float v) {
    float y = 1.5957691f * (v + 0.044715f * v * v * v);
    return v / (1.0f + __expf(-y));
}

__global__ __launch_bounds__(256)
void pack_x_kernel(const float* __restrict__ x, bf16* __restrict__ xb) {
    const int i = blockIdx.x * 256 + threadIdx.x;
    float4 v = ((const float4*)x)[i];
    bf16x4 o;
    o[0] = (bf16)v.x; o[1] = (bf16)v.y; o[2] = (bf16)v.z; o[3] = (bf16)v.w;
    ((bf16x4*)xb)[i] = o;
}

__global__ __launch_bounds__(256)
void merge_ao_kernel(const bf16* __restrict__ a, const bf16* __restrict__ b,
                     bf16* __restrict__ o) {
    const long i = ((long)blockIdx.x * 256 + threadIdx.x) * 8;
    bf16x8 va = *(const bf16x8*)&a[i];
    bf16x8 vb = *(const bf16x8*)&b[i];
    bf16x8 vo;
#pragma unroll
    for (int j = 0; j < 8; j++) vo[j] = (bf16)((float)va[j] + (float)vb[j]);
    *(bf16x8*)&o[i] = vo;
}

// ---------------------------------------------------------------------------
// merge split-K GEMM partials (+bias +residual), then LayerNorm over D=768.
// ---------------------------------------------------------------------------
template<bool FIRST>
__global__ __launch_bounds__(256)
void merge_ln_kernel(const bf16* __restrict__ pp, const float* __restrict__ bias,
                     const float* __restrict__ residf, const bf16* __restrict__ residb,
                     const float* __restrict__ gamma, const float* __restrict__ beta,
                     float* __restrict__ outf, bf16* __restrict__ outb) {
    __shared__ float sa[4], sb[4];
    const int row = blockIdx.x, t = threadIdx.x;
    const bf16* p0 = pp + (long)row * 768;
    const bf16* p1 = pp + (long)M_ * 768 + (long)row * 768;
    float v[3];
#pragma unroll
    for (int i = 0; i < 3; i++) {
        const int c = t + i * 256;
        float y = (float)p0[c] + (float)p1[c] + bias[c];
        if (FIRST) y += residf[(long)row * 768 + c];
        else       y += (float)residb[(long)row * 768 + c];
        v[i] = y;
    }
    float s  = v[0] + v[1] + v[2];
    float ss = v[0] * v[0] + v[1] * v[1] + v[2] * v[2];
#pragma unroll
    for (int o = 32; o; o >>= 1) { s += __shfl_xor(s, o); ss += __shfl_xor(ss, o); }
    if ((t & 63) == 0) { sa[t >> 6] = s; sb[t >> 6] = ss; }
    __syncthreads();
    s  = sa[0] + sa[1] + sa[2] + sa[3];
    ss = sb[0] + sb[1] + sb[2] + sb[3];
    const float mu   = s * (1.0f / 768.0f);
    const float var  = ss * (1.0f / 768.0f) - mu * mu;
    const float rstd = rsqrtf(var + 1e-5f);
#pragma unroll
    for (int i = 0; i < 3; i++) {
        const int c = t + i * 256;
        const float ov = (v[i] - mu) * rstd * gamma[c] + beta[c];
        if (FIRST) outb[(long)row * 768 + c] = (bf16)ov;
        else       outf[(long)row * 768 + c] = ov;
    }
}

__global__ __launch_bounds__(256)
void wt_all_kernel(const float* __restrict__ Wq, const float* __restrict__ Wk,
                   const float* __restrict__ Wv, const float* __restrict__ Wo,
                   const float* __restrict__ W1, const float* __restrict__ W2,
                   bf16* __restrict__ Wqkvt, bf16* __restrict__ Wot,
                   bf16* __restrict__ W1t, bf16* __restrict__ W2t) {
    int bid = blockIdx.x;
    const float* in; bf16* out; int K, N, t;
    if (bid < 576) {
        int m = bid / 144; t = bid % 144; K = 768; N = 768;
        in  = (m == 0) ? Wq : (m == 1) ? Wk : (m == 2) ? Wv : Wo;
        out = (m == 3) ? Wot : Wqkvt + (size_t)m * 768 * 768;
    } else if (bid < 1152) {
        t = bid - 576; K = 768; N = 3072; in = W1; out = W1t;
    } else {
        t = bid - 1152; K = 3072; N = 768; in = W2; out = W2t;
    }
    const int ntx = N / 64;
    const int n0 = (t % ntx) * 64, k0 = (t / ntx) * 64;

    __shared__ __align__(16) bf16 T[64][72];
    const int tt = threadIdx.x;
    const int r  = tt >> 2, c0 = (tt & 3) * 16;
    const float* src = in + (size_t)(k0 + r) * N + n0 + c0;
#pragma unroll
    for (int j = 0; j < 16; j += 4) {
        float4 v = *(const float4*)(src + j);
        T[r][c0 + j + 0] = (bf16)v.x;
        T[r][c0 + j + 1] = (bf16)v.y;
        T[r][c0 + j + 2] = (bf16)v.z;
        T[r][c0 + j + 3] = (bf16)v.w;
    }
    __syncthreads();
    bf16x8 o0, o1;
#pragma unroll
    for (int j = 0; j < 8; j++) { o0[j] = T[c0 + j][r]; o1[j] = T[c0 + 8 + j][r]; }
    bf16* dst = out + (size_t)(n0 + r) * K + k0 + c0;
    *(bf16x8*)(dst)     = o0;
    *(bf16x8*)(dst + 8) = o1;
}

// ---------------------------------------------------------------------------
// GEMM: C = A[M,K] @ Bt[N,K]^T (unchanged from R15/R16).
// ---------------------------------------------------------------------------
template<int EPI, int K, int BM, int BN, int WR, int WC, int KSPLIT>
__global__ __launch_bounds__(256)
void gemm_bt(const bf16* __restrict__ A, const bf16* __restrict__ Bt,
             const float* __restrict__ bias0, const float* __restrict__ bias1,
             const float* __restrict__ bias2,
             bf16* __restrict__ outb,
             bf16* __restrict__ qo, bf16* __restrict__ ko, bf16* __restrict__ vo) {
    constexpr int MR  = BM / WR / 16;
    constexpr int NR  = BN / WC / 16;
    constexpr int GA  = BM / 32;
    constexpr int GB  = BN / 32;
    constexpr int NPT = GA + GB;
    constexpr int KS  = K / KSPLIT;
    constexpr int NCOL = (EPI == 0) ? 2304 : (EPI == 2) ? 3072 : 768;
    constexpr int NBX  = NCOL / BN;
    __shared__ __align__(16) bf16 Al[2 * BM * 64];
    __shared__ __align__(16) bf16 Bl[2 * BN * 64];
    const int tid  = threadIdx.x;
    const int lane = tid & 63, w = tid >> 6;
    const int wr = w / WC, wc = w % WC;
    const int wg = xcd_swz(blockIdx.x, gridDim.x);
    const int ks = wg % KSPLIT;
    const int tt = wg / KSPLIT;
    const int m0 = (tt / NBX) * BM, n0 = (tt % NBX) * BN;
    const int kb = ks * KS;
    const int g = lane >> 4, q = lane & 15;
    const int srow = lane >> 3;
    const int schunk = (((lane & 7) ^ ((lane >> 3) & 7))) * 8;

    f32x4 acc[MR][NR] = {};

    const bf16* gaA = A  + (long)(m0 + w * (BM / 4) + srow) * K + kb + schunk;
    const bf16* gaB = Bt + (long)(n0 + w * (BN / 4) + srow) * K + kb + schunk;

    auto stage = [&](int buf, int kt) {
#pragma unroll
        for (int i = 0; i < GA; i++)
            gload16(gaA + kt + (long)i * 8 * K,
                    &Al[buf * BM * 64 + (w * (BM / 4) + i * 8) * 64]);
#pragma unroll
        for (int i = 0; i < GB; i++)
            gload16(gaB + kt + (long)i * 8 * K,
                    &Bl[buf * BN * 64 + (w * (BN / 4) + i * 8) * 64]);
    };
    auto compute = [&](int buf) {
#pragma unroll
        for (int c = 0; c < 2; c++) {
            const int rch = ((c * 4 + g) ^ (q & 7)) * 8;
            bf16x8 af[MR], bfr[NR];
#pragma unroll
            for (int i = 0; i < MR; i++)
                af[i] = *(const bf16x8*)
                    &Al[buf * BM * 64 + (wr * (BM / WR) + i * 16 + q) * 64 + rch];
#pragma unroll
            for (int i = 0; i < NR; i++)
                bfr[i] = *(const bf16x8*)
                    &Bl[buf * BN * 64 + (wc * (BN / WC) + i * 16 + q) * 64 + rch];
#pragma unroll
            for (int mi = 0; mi < MR; mi++)
#pragma unroll
                for (int ni = 0; ni < NR; ni++)
                    acc[mi][ni] = mfma16(af[mi], bfr[ni], acc[mi][ni]);
        }
    };

    stage(0, 0);
    stage(1, 64);
    int cur = 0;
    for (int kt = 0; kt < KS - 64; kt += 64) {
        wait_vmcnt<NPT>();
        __builtin_amdgcn_s_barrier();
        compute(cur);
        wait_lgkm0();
        __builtin_amdgcn_s_barrier();
        if (kt + 128 < KS) stage(cur, kt + 128);
        cur ^= 1;
    }
    wait_vmcnt<0>();
    __builtin_amdgcn_s_barrier();
    compute(cur);

#pragma unroll
    for (int mi = 0; mi < MR; mi++) {
        if (EPI == 0) {
            const int col0  = n0 + wc * 64;
            const int which = (col0 >= 1536) ? 2 : (col0 >= 768 ? 1 : 0);
            const int row0  = m0 + wr * (BM / WR) + mi * 16 + g * 4;
            float val[NR][4];
#pragma unroll
            for (int ni = 0; ni < NR; ni++) {
                const int dd = col0 + ni * 16 + q - which * 768;
                const float bias = (which == 0 ? bias0 : which == 1 ? bias1 : bias2)[dd];
#pragma unroll
                for (int r = 0; r < 4; r++) val[ni][r] = acc[mi][ni][r] + bias;
            }
            if (which <= 1) {
#pragma unroll
                for (int r = 0; r < 4; r++) {
                    float ss = val[0][r] * val[0][r];
#pragma unroll
                    for (int ni = 1; ni < NR; ni++) ss += val[ni][r] * val[ni][r];
                    ss += __shfl_xor(ss, 1);
                    ss += __shfl_xor(ss, 2);
                    ss += __shfl_xor(ss, 4);
                    ss += __shfl_xor(ss, 8);
                    const float rn = 1.0f / fmaxf(sqrtf(ss), 1e-12f);
#pragma unroll
                    for (int ni = 0; ni < NR; ni++) val[ni][r] *= rn;
                }
            }
            const int dd0 = col0 - which * 768;
            const int hh  = dd0 >> 6;
            const long bh = (long)(row0 >> 11) * 12 + hh;
#pragma unroll
            for (int ni = 0; ni < NR; ni++) {
                const int dk = ni * 16 + q;
                if (which == 2) {
                    bf16x4 pv;
#pragma unroll
                    for (int r = 0; r < 4; r++) pv[r] = (bf16)val[ni][r];
                    *(bf16x4*)&vo[(bh * 64 + dk) * 2048 + (row0 & 2047)] = pv;
                } else {
                    bf16* dst = (which == 0) ? qo : ko;
#pragma unroll
                    for (int r = 0; r < 4; r++)
                        dst[(bh * 2048 + ((row0 + r) & 2047)) * 64 + dk] = (bf16)val[ni][r];
                }
            }
        } else if (EPI == 2) {
#pragma unroll
            for (int ni = 0; ni < NR; ni++) {
                const int col  = n0 + wc * (BN / WC) + ni * 16 + q;
                const int row0 = m0 + wr * (BM / WR) + mi * 16 + g * 4;
                const float bias = bias0[col];
#pragma unroll
                for (int r = 0; r < 4; r++) {
                    const float v = acc[mi][ni][r] + bias;
                    outb[(long)(row0 + r) * 3072 + col] = (bf16)gelu_f(v);
                }
            }
        } else {  // EPI 1/3 with KSPLIT: raw bf16 partial
#pragma unroll
            for (int ni = 0; ni < NR; ni++) {
                const int col  = n0 + wc * (BN / WC) + ni * 16 + q;
                const int row0 = m0 + wr * (BM / WR) + mi * 16 + g * 4;
#pragma unroll
                for (int r = 0; r < 4; r++)
                    outb[(long)ks * M_ * 768 + (long)(row0 + r) * 768 + col] =
                        (bf16)acc[mi][ni][r];
            }
        }
    }
}

// ---------------------------------------------------------------------------
// Attention split-K over keys (PV linear, no softmax), skewed qk||pv pipe.
// Unpadded 64-wide LDS rows + within-row XOR chunk swizzle (conflict-free,
// 40960 B total). __launch_bounds__(256,3): VGPR cap 170 -> NO spill (the
// R17 (256,4) variant capped at 128 and spilled 152MB of scratch); LDS
// still permits a 4th block opportunistically when registers allow.
// Grid 768 = 2 kv-halves x 16 qblocks x 24 bh.
// ---------------------------------------------------------------------------
__global__ __launch_bounds__(256, 3)
void attn_kernel(const bf16* __restrict__ Qn, const bf16* __restrict__ Kn,
                 const bf16* __restrict__ Vt, bf16* __restrict__ AOp) {
    const int wg  = xcd_swz(blockIdx.x, gridDim.x);
    const int bh  = wg >> 5;
    const int rem = wg & 31;
    const int kvhalf = rem >> 4;
    const int qblk   = rem & 15;
    const int tid = threadIdx.x, lane = tid & 63, w = tid >> 6;
    const int g = lane >> 4, q15 = lane & 15;
    const int qbase = qblk * 128 + w * 32;
    const int kv0   = kvhalf * 1024;
    constexpr int NT = 16;

    __shared__ __align__(16) bf16 Kl[2][64][64];
    __shared__ __align__(16) bf16 Vl[2][64][64];
    __shared__ __align__(16) bf16 Pl[4][16][64];
    bf16 (*Pw)[64] = Pl[w];

    const bf16* Qp = Qn + (long)bh * S_ * 64;
    const bf16* Kp = Kn + (long)bh * S_ * 64 + (long)kv0 * 64;
    const bf16* Vp = Vt + (long)bh * 64 * S_ + kv0;
    bf16* AOo = AOp + (long)kvhalf * M_ * D_;

    const int srow = tid >> 3, scol = (tid & 7) * 8;
    const int ssw  = (((lane & 7) ^ ((lane >> 3) & 7))) * 8;
    const int q7   = q15 & 7;

    bf16x8 qf00 = *(const bf16x8*)&Qp[(long)(qbase + q15) * 64 + g * 8];
    bf16x8 qf01 = *(const bf16x8*)&Qp[(long)(qbase + q15) * 64 + 32 + g * 8];
    bf16x8 qf10 = *(const bf16x8*)&Qp[(long)(qbase + 16 + q15) * 64 + g * 8];
    bf16x8 qf11 = *(const bf16x8*)&Qp[(long)(qbase + 16 + q15) * 64 + 32 + g * 8];

    f32x4 o0[4] = {}, o1[4] = {};
    bf16x8 kf[4][2], vf[4][2];
    bf16x8 aK0, aK1, aV0, aV1, bK0, bK1, bV0, bV1;

    auto gloadA = [&](int kt) {
        aK0 = *(const bf16x8*)&Kp[(long)(kt + srow) * 64 + scol];
        aK1 = *(const bf16x8*)&Kp[(long)(kt + 32 + srow) * 64 + scol];
        aV0 = *(const bf16x8*)&Vp[(long)srow * S_ + kt + scol];
        aV1 = *(const bf16x8*)&Vp[(long)(32 + srow) * S_ + kt + scol];
    };
    auto gloadB = [&](int kt) {
        bK0 = *(const bf16x8*)&Kp[(long)(kt + srow) * 64 + scol];
        bK1 = *(const bf16x8*)&Kp[(long)(kt + 32 + srow) * 64 + scol];
        bV0 = *(const bf16x8*)&Vp[(long)srow * S_ + kt + scol];
        bV1 = *(const bf16x8*)&Vp[(long)(32 + srow) * S_ + kt + scol];
    };
    auto stageA = [&](int buf) {
        *(bf16x8*)&Kl[buf][srow][ssw]      = aK0;
        *(bf16x8*)&Kl[buf][32 + srow][ssw] = aK1;
        *(bf16x8*)&Vl[buf][srow][ssw]      = aV0;
        *(bf16x8*)&Vl[buf][32 + srow][ssw] = aV1;
    };
    auto stageB = [&](int buf) {
        *(bf16x8*)&Kl[buf][srow][ssw]      = bK0;
        *(bf16x8*)&Kl[buf][32 + srow][ssw] = bK1;
        *(bf16x8*)&Vl[buf][srow][ssw]      = bV0;
        *(bf16x8*)&Vl[buf][32 + srow][ssw] = bV1;
    };

    auto loadKf = [&](int cur) {
#pragma unroll
        for (int ni = 0; ni < 4; ni++)
#pragma unroll
            for (int c = 0; c < 2; c++)
                kf[ni][c] = *(const bf16x8*)
                    &Kl[cur][ni * 16 + q15][(((c * 4 + g) ^ q7)) * 8];
    };
    auto loadVf = [&](int cur) {
#pragma unroll
        for (int ni = 0; ni < 4; ni++)
#pragma unroll
            for (int c = 0; c < 2; c++)
                vf[ni][c] = *(const bf16x8*)
                    &Vl[cur][ni * 16 + q15][(((c * 4 + g) ^ q7)) * 8];
    };
    auto qk = [&](bf16x8 qa, bf16x8 qb) {
        f32x4 s[4];
#pragma unroll
        for (int ni = 0; ni < 4; ni++) {
            s[ni] = mfma16(kf[ni][0], qa, f32x4{0.f, 0.f, 0.f, 0.f});
            s[ni] = mfma16(kf[ni][1], qb, s[ni]);
        }
#pragma unroll
        for (int ni = 0; ni < 4; ni++) {
            bf16x4 p4;
#pragma unroll
            for (int r = 0; r < 4; r++) { float v = s[ni][r]; p4[r] = (bf16)(v * v); }
            const int ch = (ni * 2 + (g >> 1)) ^ q7;
            *(bf16x4*)&Pw[q15][ch * 8 + (g & 1) * 4] = p4;
        }
    };
    auto pv = [&](f32x4 (&o)[4]) {
        bf16x8 pf0 = *(const bf16x8*)&Pw[q15][((g ^ q7)) * 8];
        bf16x8 pf1 = *(const bf16x8*)&Pw[q15][(((4 + g) ^ q7)) * 8];
#pragma unroll
        for (int ni = 0; ni < 4; ni++) {
            o[ni] = mfma16(pf0, vf[ni][0], o[ni]);
            o[ni] = mfma16(pf1, vf[ni][1], o[ni]);
        }
    };

    gloadA(0);
    stageA(0);
    gloadB(64);
    wait_lgkm0(); __builtin_amdgcn_s_barrier();
    stageB(1);
    gloadA(2 * 64);
    loadKf(0); qk(qf00, qf01);
    loadVf(0); pv(o0);
    qk(qf10, qf11);

    for (int t = 1; t <= NT - 3; t += 2) {
        pv(o1);
        wait_lgkm0(); __builtin_amdgcn_s_barrier();
        stageA(0);
        gloadB((t + 2) * 64);
        loadKf(1); qk(qf00, qf01);
        loadVf(1); pv(o0);
        qk(qf10, qf11);

        pv(o1);
        wait_lgkm0(); __builtin_amdgcn_s_barrier();
        stageB(1);
        if (t + 3 < NT) gloadA((t + 3) * 64);
        loadKf(0); qk(qf00, qf01);
        loadVf(0); pv(o0);
        qk(qf10, qf11);
    }
    pv(o1);
    wait_lgkm0(); __builtin_amdgcn_s_barrier();
    loadKf(1); qk(qf00, qf01);
    loadVf(1); pv(o0);
    qk(qf10, qf11);
    pv(o1);

    const int b = bh / 12, h = bh % 12;
#pragma unroll
    for (int ni = 0; ni < 4; ni++)
#pragma unroll
        for (int r = 0; r < 4; r++) {
            const int s0r = qbase + g * 4 + r;
            AOo[((long)b * S_ + s0r) * D_ + h * 64 + ni * 16 + q15] = (bf16)o0[ni][r];
            const int s1r = qbase + 16 + g * 4 + r;
            AOo[((long)b * S_ + s1r) * D_ + h * 64 + ni * 16 + q15] = (bf16)o1[ni][r];
        }
}

extern "C" void kernel_launch(void* const* d_in, const int* in_sizes, int n_in,
                              void* d_out, int out_size, void* d_ws, size_t ws_size,
                              hipStream_t stream) {
    const float* x     = (const float*)d_in[0];
    const float* Wq    = (const float*)d_in[1];
    const float* bq    = (const float*)d_in[2];
    const float* Wk    = (const float*)d_in[3];
    const float* bk    = (const float*)d_in[4];
    const float* Wv    = (const float*)d_in[5];
    const float* bv    = (const float*)d_in[6];
    const float* Wo    = (const float*)d_in[7];
    const float* bo    = (const float*)d_in[8];
    const float* W1    = (const float*)d_in[9];
    const float* b1    = (const float*)d_in[10];
    const float* W2    = (const float*)d_in[11];
    const float* b2    = (const float*)d_in[12];
    const float* gamma = (const float*)d_in[13];
    const float* beta  = (const float*)d_in[14];

    char* p = (char*)d_ws;
    auto alloc = [&](size_t bytes) -> void* {
        void* r = p;
        p += (bytes + 255) & ~(size_t)255;
        return r;
    };
    bf16*  Xb    = (bf16*)alloc((size_t)M_ * D_ * 2);
    bf16*  Wqkvt = (bf16*)alloc((size_t)2304 * 768 * 2);
    bf16*  Wot   = (bf16*)alloc((size_t)768 * 768 * 2);
    bf16*  W1t   = (bf16*)alloc((size_t)3072 * 768 * 2);
    bf16*  W2t   = (bf16*)alloc((size_t)768 * 3072 * 2);
    bf16*  Qh    = (bf16*)alloc((size_t)BH_ * S_ * 64 * 2);
    bf16*  Kh    = (bf16*)alloc((size_t)BH_ * S_ * 64 * 2);
    bf16*  Vt    = (bf16*)alloc((size_t)BH_ * S_ * 64 * 2);
    bf16*  AOp   = (bf16*)alloc((size_t)2 * M_ * D_ * 2);  // attn partials
    bf16*  AO    = (bf16*)alloc((size_t)M_ * D_ * 2);
    bf16*  pp    = (bf16*)alloc((size_t)2 * M_ * 768 * 2); // GEMM K-split partials
    bf16*  x1b   = (bf16*)alloc((size_t)M_ * D_ * 2);
    bf16*  hbuf  = (bf16*)alloc((size_t)M_ * DFF_ * 2);

    pack_x_kernel<<<(M_ * D_) / 1024, 256, 0, stream>>>(x, Xb);
    wt_all_kernel<<<1728, 256, 0, stream>>>(Wq, Wk, Wv, Wo, W1, W2,
                                            Wqkvt, Wot, W1t, W2t);

    // QKV: 64x128 tiles -> 1152 blocks (48KB LDS, 3/CU)
    gemm_bt<0, 768, 64, 128, 2, 2, 1><<<64 * 18, 256, 0, stream>>>(
        Xb, Wqkvt, bq, bk, bv, nullptr, Qh, Kh, Vt);

    // attention: 768 blocks, split-K over keys, then merge
    attn_kernel<<<2 * 16 * BH_, 256, 0, stream>>>(Qh, Kh, Vt, AOp);
    merge_ao_kernel<<<(M_ * D_) / 2048, 256, 0, stream>>>(
        AOp, AOp + (size_t)M_ * D_, AO);

    // Wo: 64x128 tiles + K-split x2 -> 768 blocks; merge + bias + resid + LN1
    gemm_bt<1, 768, 64, 128, 2, 2, 2><<<64 * 6 * 2, 256, 0, stream>>>(
        AO, Wot, nullptr, nullptr, nullptr, pp, nullptr, nullptr, nullptr);
    merge_ln_kernel<true><<<M_, 256, 0, stream>>>(
        pp, bo, x, nullptr, gamma, beta, nullptr, x1b);

    // FFN1: 64x128 tiles -> 1536 blocks
    gemm_bt<2, 768, 64, 128, 2, 2, 1><<<64 * 24, 256, 0, stream>>>(
        x1b, W1t, b1, nullptr, nullptr, hbuf, nullptr, nullptr, nullptr);

    // FFN2: 64x128 tiles + K-split x2 -> 768 blocks; merge + bias + resid + LN2
    gemm_bt<3, 3072, 64, 128, 2, 2, 2><<<64 * 6 * 2, 256, 0, stream>>>(
        hbuf, W2t, nullptr, nullptr, nullptr, pp, nullptr, nullptr, nullptr);
    merge_ln_kernel<false><<<M_, 256, 0, stream>>>(
        pp, b2, nullptr, x1b, gamma, beta, (float*)d_out, nullptr);
}

// Round 19
// 155.133 us; speedup vs baseline: 1.2788x; 1.0051x over previous
//
#include <hip/hip_runtime.h>
#include <math.h>

using bf16   = __bf16;
using bf16x8 = __attribute__((ext_vector_type(8))) __bf16;
using bf16x4 = __attribute__((ext_vector_type(4))) __bf16;
using f32x4  = __attribute__((ext_vector_type(4))) float;

constexpr int S_   = 2048;
constexpr int D_   = 768;
constexpr int DFF_ = 3072;
constexpr int M_   = 4096;   // B*S
constexpr int BH_  = 24;     // B*H

__device__ __forceinline__ f32x4 mfma16(bf16x8 a, bf16x8 b, f32x4 c) {
    return __builtin_amdgcn_mfma_f32_16x16x32_bf16(a, b, c, 0, 0, 0);
}

__device__ __forceinline__ void gload16(const bf16* g, bf16* l) {
    __builtin_amdgcn_global_load_lds(
        (const __attribute__((address_space(1))) void*)g,
        (__attribute__((address_space(3))) void*)l, 16, 0, 0);
}

template<int N> __device__ __forceinline__ void wait_vmcnt() {
    if constexpr (N == 0)      asm volatile("s_waitcnt vmcnt(0)" ::: "memory");
    else if constexpr (N == 4) asm volatile("s_waitcnt vmcnt(4)" ::: "memory");
    else if constexpr (N == 6) asm volatile("s_waitcnt vmcnt(6)" ::: "memory");
    else if constexpr (N == 8) asm volatile("s_waitcnt vmcnt(8)" ::: "memory");
    else static_assert(N == 0, "unsupported vmcnt");
}
__device__ __forceinline__ void wait_lgkm0() {
    asm volatile("s_waitcnt lgkmcnt(0)" ::: "memory");
}

__device__ __forceinline__ int xcd_swz(int orig, int nwg) {
    return (orig & 7) * (nwg >> 3) + (orig >> 3);
}

__device__ __forceinline__ float gelu_f(float v) {
    float y = 1.5957691f * (v + 0.044715f * v * v * v);
    return v / (1.0f + __expf(-y));
}

__global__ __launch_bounds__(256)
void pack_x_kernel(const float* __restrict__ x, bf16* __restrict__ xb) {
    const int i = blockIdx.x * 256 + threadIdx.x;
    float4 v = ((const float4*)x)[i];
    bf16x4 o;
    o[0] = (bf16)v.x; o[1] = (bf16)v.y; o[2] = (bf16)v.z; o[3] = (bf16)v.w;
    ((bf16x4*)xb)[i] = o;
}

__global__ __launch_bounds__(256)
void merge_ao_kernel(const bf16* __restrict__ a, const bf16* __restrict__ b,
                     bf16* __restrict__ o) {
    const long i = ((long)blockIdx.x * 256 + threadIdx.x) * 8;
    bf16x8 va = *(const bf16x8*)&a[i];
    bf16x8 vb = *(const bf16x8*)&b[i];
    bf16x8 vo;
#pragma unroll
    for (int j = 0; j < 8; j++) vo[j] = (bf16)((float)va[j] + (float)vb[j]);
    *(bf16x8*)&o[i] = vo;
}

// ---------------------------------------------------------------------------
// merge split-K GEMM partials (+bias +residual), then LayerNorm over D=768.
// ---------------------------------------------------------------------------
template<bool FIRST>
__global__ __launch_bounds__(256)
void merge_ln_kernel(const bf16* __restrict__ pp, const float* __restrict__ bias,
                     const float* __restrict__ residf, const bf16* __restrict__ residb,
                     const float* __restrict__ gamma, const float* __restrict__ beta,
                     float* __restrict__ outf, bf16* __restrict__ outb) {
    __shared__ float sa[4], sb[4];
    const int row = blockIdx.x, t = threadIdx.x;
    const bf16* p0 = pp + (long)row * 768;
    const bf16* p1 = pp + (long)M_ * 768 + (long)row * 768;
    float v[3];
#pragma unroll
    for (int i = 0; i < 3; i++) {
        const int c = t + i * 256;
        float y = (float)p0[c] + (float)p1[c] + bias[c];
        if (FIRST) y += residf[(long)row * 768 + c];
        else       y += (float)residb[(long)row * 768 + c];
        v[i] = y;
    }
    float s  = v[0] + v[1] + v[2];
    float ss = v[0] * v[0] + v[1] * v[1] + v[2] * v[2];
#pragma unroll
    for (int o = 32; o; o >>= 1) { s += __shfl_xor(s, o); ss += __shfl_xor(ss, o); }
    if ((t & 63) == 0) { sa[t >> 6] = s; sb[t >> 6] = ss; }
    __syncthreads();
    s  = sa[0] + sa[1] + sa[2] + sa[3];
    ss = sb[0] + sb[1] + sb[2] + sb[3];
    const float mu   = s * (1.0f / 768.0f);
    const float var  = ss * (1.0f / 768.0f) - mu * mu;
    const float rstd = rsqrtf(var + 1e-5f);
#pragma unroll
    for (int i = 0; i < 3; i++) {
        const int c = t + i * 256;
        const float ov = (v[i] - mu) * rstd * gamma[c] + beta[c];
        if (FIRST) outb[(long)row * 768 + c] = (bf16)ov;
        else       outf[(long)row * 768 + c] = ov;
    }
}

__global__ __launch_bounds__(256)
void wt_all_kernel(const float* __restrict__ Wq, const float* __restrict__ Wk,
                   const float* __restrict__ Wv, const float* __restrict__ Wo,
                   const float* __restrict__ W1, const float* __restrict__ W2,
                   bf16* __restrict__ Wqkvt, bf16* __restrict__ Wot,
                   bf16* __restrict__ W1t, bf16* __restrict__ W2t) {
    int bid = blockIdx.x;
    const float* in; bf16* out; int K, N, t;
    if (bid < 576) {
        int m = bid / 144; t = bid % 144; K = 768; N = 768;
        in  = (m == 0) ? Wq : (m == 1) ? Wk : (m == 2) ? Wv : Wo;
        out = (m == 3) ? Wot : Wqkvt + (size_t)m * 768 * 768;
    } else if (bid < 1152) {
        t = bid - 576; K = 768; N = 3072; in = W1; out = W1t;
    } else {
        t = bid - 1152; K = 3072; N = 768; in = W2; out = W2t;
    }
    const int ntx = N / 64;
    const int n0 = (t % ntx) * 64, k0 = (t / ntx) * 64;

    __shared__ __align__(16) bf16 T[64][72];
    const int tt = threadIdx.x;
    const int r  = tt >> 2, c0 = (tt & 3) * 16;
    const float* src = in + (size_t)(k0 + r) * N + n0 + c0;
#pragma unroll
    for (int j = 0; j < 16; j += 4) {
        float4 v = *(const float4*)(src + j);
        T[r][c0 + j + 0] = (bf16)v.x;
        T[r][c0 + j + 1] = (bf16)v.y;
        T[r][c0 + j + 2] = (bf16)v.z;
        T[r][c0 + j + 3] = (bf16)v.w;
    }
    __syncthreads();
    bf16x8 o0, o1;
#pragma unroll
    for (int j = 0; j < 8; j++) { o0[j] = T[c0 + j][r]; o1[j] = T[c0 + 8 + j][r]; }
    bf16* dst = out + (size_t)(n0 + r) * K + k0 + c0;
    *(bf16x8*)(dst)     = o0;
    *(bf16x8*)(dst + 8) = o1;
}

// ---------------------------------------------------------------------------
// GEMM: C = A[M,K] @ Bt[N,K]^T (unchanged from R15/R16/R18).
// ---------------------------------------------------------------------------
template<int EPI, int K, int BM, int BN, int WR, int WC, int KSPLIT>
__global__ __launch_bounds__(256)
void gemm_bt(const bf16* __restrict__ A, const bf16* __restrict__ Bt,
             const float* __restrict__ bias0, const float* __restrict__ bias1,
             const float* __restrict__ bias2,
             bf16* __restrict__ outb,
             bf16* __restrict__ qo, bf16* __restrict__ ko, bf16* __restrict__ vo) {
    constexpr int MR  = BM / WR / 16;
    constexpr int NR  = BN / WC / 16;
    constexpr int GA  = BM / 32;
    constexpr int GB  = BN / 32;
    constexpr int NPT = GA + GB;
    constexpr int KS  = K / KSPLIT;
    constexpr int NCOL = (EPI == 0) ? 2304 : (EPI == 2) ? 3072 : 768;
    constexpr int NBX  = NCOL / BN;
    __shared__ __align__(16) bf16 Al[2 * BM * 64];
    __shared__ __align__(16) bf16 Bl[2 * BN * 64];
    const int tid  = threadIdx.x;
    const int lane = tid & 63, w = tid >> 6;
    const int wr = w / WC, wc = w % WC;
    const int wg = xcd_swz(blockIdx.x, gridDim.x);
    const int ks = wg % KSPLIT;
    const int tt = wg / KSPLIT;
    const int m0 = (tt / NBX) * BM, n0 = (tt % NBX) * BN;
    const int kb = ks * KS;
    const int g = lane >> 4, q = lane & 15;
    const int srow = lane >> 3;
    const int schunk = (((lane & 7) ^ ((lane >> 3) & 7))) * 8;

    f32x4 acc[MR][NR] = {};

    const bf16* gaA = A  + (long)(m0 + w * (BM / 4) + srow) * K + kb + schunk;
    const bf16* gaB = Bt + (long)(n0 + w * (BN / 4) + srow) * K + kb + schunk;

    auto stage = [&](int buf, int kt) {
#pragma unroll
        for (int i = 0; i < GA; i++)
            gload16(gaA + kt + (long)i * 8 * K,
                    &Al[buf * BM * 64 + (w * (BM / 4) + i * 8) * 64]);
#pragma unroll
        for (int i = 0; i < GB; i++)
            gload16(gaB + kt + (long)i * 8 * K,
                    &Bl[buf * BN * 64 + (w * (BN / 4) + i * 8) * 64]);
    };
    auto compute = [&](int buf) {
#pragma unroll
        for (int c = 0; c < 2; c++) {
            const int rch = ((c * 4 + g) ^ (q & 7)) * 8;
            bf16x8 af[MR], bfr[NR];
#pragma unroll
            for (int i = 0; i < MR; i++)
                af[i] = *(const bf16x8*)
                    &Al[buf * BM * 64 + (wr * (BM / WR) + i * 16 + q) * 64 + rch];
#pragma unroll
            for (int i = 0; i < NR; i++)
                bfr[i] = *(const bf16x8*)
                    &Bl[buf * BN * 64 + (wc * (BN / WC) + i * 16 + q) * 64 + rch];
#pragma unroll
            for (int mi = 0; mi < MR; mi++)
#pragma unroll
                for (int ni = 0; ni < NR; ni++)
                    acc[mi][ni] = mfma16(af[mi], bfr[ni], acc[mi][ni]);
        }
    };

    stage(0, 0);
    stage(1, 64);
    int cur = 0;
    for (int kt = 0; kt < KS - 64; kt += 64) {
        wait_vmcnt<NPT>();
        __builtin_amdgcn_s_barrier();
        compute(cur);
        wait_lgkm0();
        __builtin_amdgcn_s_barrier();
        if (kt + 128 < KS) stage(cur, kt + 128);
        cur ^= 1;
    }
    wait_vmcnt<0>();
    __builtin_amdgcn_s_barrier();
    compute(cur);

#pragma unroll
    for (int mi = 0; mi < MR; mi++) {
        if (EPI == 0) {
            const int col0  = n0 + wc * 64;
            const int which = (col0 >= 1536) ? 2 : (col0 >= 768 ? 1 : 0);
            const int row0  = m0 + wr * (BM / WR) + mi * 16 + g * 4;
            float val[NR][4];
#pragma unroll
            for (int ni = 0; ni < NR; ni++) {
                const int dd = col0 + ni * 16 + q - which * 768;
                const float bias = (which == 0 ? bias0 : which == 1 ? bias1 : bias2)[dd];
#pragma unroll
                for (int r = 0; r < 4; r++) val[ni][r] = acc[mi][ni][r] + bias;
            }
            if (which <= 1) {
#pragma unroll
                for (int r = 0; r < 4; r++) {
                    float ss = val[0][r] * val[0][r];
#pragma unroll
                    for (int ni = 1; ni < NR; ni++) ss += val[ni][r] * val[ni][r];
                    ss += __shfl_xor(ss, 1);
                    ss += __shfl_xor(ss, 2);
                    ss += __shfl_xor(ss, 4);
                    ss += __shfl_xor(ss, 8);
                    const float rn = 1.0f / fmaxf(sqrtf(ss), 1e-12f);
#pragma unroll
                    for (int ni = 0; ni < NR; ni++) val[ni][r] *= rn;
                }
            }
            const int dd0 = col0 - which * 768;
            const int hh  = dd0 >> 6;
            const long bh = (long)(row0 >> 11) * 12 + hh;
#pragma unroll
            for (int ni = 0; ni < NR; ni++) {
                const int dk = ni * 16 + q;
                if (which == 2) {
                    bf16x4 pv;
#pragma unroll
                    for (int r = 0; r < 4; r++) pv[r] = (bf16)val[ni][r];
                    *(bf16x4*)&vo[(bh * 64 + dk) * 2048 + (row0 & 2047)] = pv;
                } else {
                    bf16* dst = (which == 0) ? qo : ko;
#pragma unroll
                    for (int r = 0; r < 4; r++)
                        dst[(bh * 2048 + ((row0 + r) & 2047)) * 64 + dk] = (bf16)val[ni][r];
                }
            }
        } else if (EPI == 2) {
#pragma unroll
            for (int ni = 0; ni < NR; ni++) {
                const int col  = n0 + wc * (BN / WC) + ni * 16 + q;
                const int row0 = m0 + wr * (BM / WR) + mi * 16 + g * 4;
                const float bias = bias0[col];
#pragma unroll
                for (int r = 0; r < 4; r++) {
                    const float v = acc[mi][ni][r] + bias;
                    outb[(long)(row0 + r) * 3072 + col] = (bf16)gelu_f(v);
                }
            }
        } else {  // EPI 1/3 with KSPLIT: raw bf16 partial
#pragma unroll
            for (int ni = 0; ni < NR; ni++) {
                const int col  = n0 + wc * (BN / WC) + ni * 16 + q;
                const int row0 = m0 + wr * (BM / WR) + mi * 16 + g * 4;
#pragma unroll
                for (int r = 0; r < 4; r++)
                    outb[(long)ks * M_ * 768 + (long)(row0 + r) * 768 + col] =
                        (bf16)acc[mi][ni][r];
            }
        }
    }
}

// ---------------------------------------------------------------------------
// Attention split-K over keys (PV linear, no softmax).
// Staging now via global_load_lds with PRE-SWIZZLED GLOBAL SOURCE (lane l
// loads chunk (l&7)^(l>>3) of its row; linear LDS write = swizzled content;
// reads use chunk^(row&7) as in R18). Each wave owns 16 rows of K and V:
// 2+2 gload16 per tile (NPT=4), counted-vmcnt double buffer, never drains
// mid-loop. Removes 4 ds_write_b128/wave/tile (-12.5% of the LDS-issue
// bottleneck) and the 8 staging registers. LDS 40960 B.
// Grid 768 = 2 kv-halves x 16 qblocks x 24 bh.
// ---------------------------------------------------------------------------
__global__ __launch_bounds__(256, 3)
void attn_kernel(const bf16* __restrict__ Qn, const bf16* __restrict__ Kn,
                 const bf16* __restrict__ Vt, bf16* __restrict__ AOp) {
    const int wg  = xcd_swz(blockIdx.x, gridDim.x);
    const int bh  = wg >> 5;
    const int rem = wg & 31;
    const int kvhalf = rem >> 4;
    const int qblk   = rem & 15;
    const int tid = threadIdx.x, lane = tid & 63, w = tid >> 6;
    const int g = lane >> 4, q15 = lane & 15;
    const int qbase = qblk * 128 + w * 32;
    const int kv0   = kvhalf * 1024;
    constexpr int NT = 16;

    __shared__ __align__(16) bf16 Kl[2][64][64];
    __shared__ __align__(16) bf16 Vl[2][64][64];
    __shared__ __align__(16) bf16 Pl[4][16][64];
    bf16 (*Pw)[64] = Pl[w];

    const bf16* Qp = Qn + (long)bh * S_ * 64;
    const bf16* Kp = Kn + (long)bh * S_ * 64 + (long)kv0 * 64;
    const bf16* Vp = Vt + (long)bh * 64 * S_ + kv0;
    bf16* AOo = AOp + (long)kvhalf * M_ * D_;

    const int grow = lane >> 3;                              // 0..7
    const int gch  = (((lane & 7) ^ (lane >> 3))) * 8;       // swizzled source chunk
    const int q7   = q15 & 7;

    // per-lane swizzled global bases for this wave's 16 rows of K and V
    const bf16* gK = Kp + (long)(w * 16 + grow) * 64 + gch;
    const bf16* gV = Vp + (long)(w * 16 + grow) * S_ + gch;

    bf16x8 qf00 = *(const bf16x8*)&Qp[(long)(qbase + q15) * 64 + g * 8];
    bf16x8 qf01 = *(const bf16x8*)&Qp[(long)(qbase + q15) * 64 + 32 + g * 8];
    bf16x8 qf10 = *(const bf16x8*)&Qp[(long)(qbase + 16 + q15) * 64 + g * 8];
    bf16x8 qf11 = *(const bf16x8*)&Qp[(long)(qbase + 16 + q15) * 64 + 32 + g * 8];

    f32x4 o0[4] = {}, o1[4] = {};
    bf16x8 kf[4][2], vf[4][2];

    // stage tile kt into buf: 2 gloads K (rows w*16, w*16+8) + 2 gloads V
    auto stage = [&](int buf, int kt) {
        gload16(gK + (long)kt * 64,            &Kl[buf][w * 16][0]);
        gload16(gK + (long)kt * 64 + 8 * 64,   &Kl[buf][w * 16 + 8][0]);
        gload16(gV + kt,                       &Vl[buf][w * 16][0]);
        gload16(gV + kt + 8 * S_,              &Vl[buf][w * 16 + 8][0]);
    };

    auto loadKf = [&](int cur) {
#pragma unroll
        for (int ni = 0; ni < 4; ni++)
#pragma unroll
            for (int c = 0; c < 2; c++)
                kf[ni][c] = *(const bf16x8*)
                    &Kl[cur][ni * 16 + q15][(((c * 4 + g) ^ q7)) * 8];
    };
    auto loadVf = [&](int cur) {
#pragma unroll
        for (int ni = 0; ni < 4; ni++)
#pragma unroll
            for (int c = 0; c < 2; c++)
                vf[ni][c] = *(const bf16x8*)
                    &Vl[cur][ni * 16 + q15][(((c * 4 + g) ^ q7)) * 8];
    };
    auto qk = [&](bf16x8 qa, bf16x8 qb) {
        f32x4 s[4];
#pragma unroll
        for (int ni = 0; ni < 4; ni++) {
            s[ni] = mfma16(kf[ni][0], qa, f32x4{0.f, 0.f, 0.f, 0.f});
            s[ni] = mfma16(kf[ni][1], qb, s[ni]);
        }
#pragma unroll
        for (int ni = 0; ni < 4; ni++) {
            bf16x4 p4;
#pragma unroll
            for (int r = 0; r < 4; r++) { float v = s[ni][r]; p4[r] = (bf16)(v * v); }
            const int ch = (ni * 2 + (g >> 1)) ^ q7;
            *(bf16x4*)&Pw[q15][ch * 8 + (g & 1) * 4] = p4;
        }
    };
    auto pv = [&](f32x4 (&o)[4]) {
        bf16x8 pf0 = *(const bf16x8*)&Pw[q15][((g ^ q7)) * 8];
        bf16x8 pf1 = *(const bf16x8*)&Pw[q15][(((4 + g) ^ q7)) * 8];
#pragma unroll
        for (int ni = 0; ni < 4; ni++) {
            o[ni] = mfma16(pf0, vf[ni][0], o[ni]);
            o[ni] = mfma16(pf1, vf[ni][1], o[ni]);
        }
    };
    auto compute = [&](int cur) {
        loadKf(cur);
        qk(qf00, qf01);
        loadVf(cur);
        pv(o0);
        qk(qf10, qf11);
        pv(o1);
    };

    // counted-vmcnt pipeline: tiles t and t+1 always in flight
    stage(0, 0);
    stage(1, 64);
    int cur = 0;
    for (int t = 0; t < NT - 1; t++) {
        wait_vmcnt<4>();                    // tile t landed; t+1 in flight
        __builtin_amdgcn_s_barrier();
        compute(cur);
        wait_lgkm0();
        __builtin_amdgcn_s_barrier();
        if (t + 2 < NT) stage(cur, (t + 2) * 64);
        cur ^= 1;
    }
    wait_vmcnt<0>();
    __builtin_amdgcn_s_barrier();
    compute(cur);

    const int b = bh / 12, h = bh % 12;
#pragma unroll
    for (int ni = 0; ni < 4; ni++)
#pragma unroll
        for (int r = 0; r < 4; r++) {
            const int s0r = qbase + g * 4 + r;
            AOo[((long)b * S_ + s0r) * D_ + h * 64 + ni * 16 + q15] = (bf16)o0[ni][r];
            const int s1r = qbase + 16 + g * 4 + r;
            AOo[((long)b * S_ + s1r) * D_ + h * 64 + ni * 16 + q15] = (bf16)o1[ni][r];
        }
}

extern "C" void kernel_launch(void* const* d_in, const int* in_sizes, int n_in,
                              void* d_out, int out_size, void* d_ws, size_t ws_size,
                              hipStream_t stream) {
    const float* x     = (const float*)d_in[0];
    const float* Wq    = (const float*)d_in[1];
    const float* bq    = (const float*)d_in[2];
    const float* Wk    = (const float*)d_in[3];
    const float* bk    = (const float*)d_in[4];
    const float* Wv    = (const float*)d_in[5];
    const float* bv    = (const float*)d_in[6];
    const float* Wo    = (const float*)d_in[7];
    const float* bo    = (const float*)d_in[8];
    const float* W1    = (const float*)d_in[9];
    const float* b1    = (const float*)d_in[10];
    const float* W2    = (const float*)d_in[11];
    const float* b2    = (const float*)d_in[12];
    const float* gamma = (const float*)d_in[13];
    const float* beta  = (const float*)d_in[14];

    char* p = (char*)d_ws;
    auto alloc = [&](size_t bytes) -> void* {
        void* r = p;
        p += (bytes + 255) & ~(size_t)255;
        return r;
    };
    bf16*  Xb    = (bf16*)alloc((size_t)M_ * D_ * 2);
    bf16*  Wqkvt = (bf16*)alloc((size_t)2304 * 768 * 2);
    bf16*  Wot   = (bf16*)alloc((size_t)768 * 768 * 2);
    bf16*  W1t   = (bf16*)alloc((size_t)3072 * 768 * 2);
    bf16*  W2t   = (bf16*)alloc((size_t)768 * 3072 * 2);
    bf16*  Qh    = (bf16*)alloc((size_t)BH_ * S_ * 64 * 2);
    bf16*  Kh    = (bf16*)alloc((size_t)BH_ * S_ * 64 * 2);
    bf16*  Vt    = (bf16*)alloc((size_t)BH_ * S_ * 64 * 2);
    bf16*  AOp   = (bf16*)alloc((size_t)2 * M_ * D_ * 2);  // attn partials
    bf16*  AO    = (bf16*)alloc((size_t)M_ * D_ * 2);
    bf16*  pp    = (bf16*)alloc((size_t)2 * M_ * 768 * 2); // GEMM K-split partials
    bf16*  x1b   = (bf16*)alloc((size_t)M_ * D_ * 2);
    bf16*  hbuf  = (bf16*)alloc((size_t)M_ * DFF_ * 2);

    pack_x_kernel<<<(M_ * D_) / 1024, 256, 0, stream>>>(x, Xb);
    wt_all_kernel<<<1728, 256, 0, stream>>>(Wq, Wk, Wv, Wo, W1, W2,
                                            Wqkvt, Wot, W1t, W2t);

    // QKV: 64x128 tiles -> 1152 blocks (48KB LDS, 3/CU)
    gemm_bt<0, 768, 64, 128, 2, 2, 1><<<64 * 18, 256, 0, stream>>>(
        Xb, Wqkvt, bq, bk, bv, nullptr, Qh, Kh, Vt);

    // attention: 768 blocks, split-K over keys, then merge
    attn_kernel<<<2 * 16 * BH_, 256, 0, stream>>>(Qh, Kh, Vt, AOp);
    merge_ao_kernel<<<(M_ * D_) / 2048, 256, 0, stream>>>(
        AOp, AOp + (size_t)M_ * D_, AO);

    // Wo: 64x128 tiles + K-split x2 -> 768 blocks; merge + bias + resid + LN1
    gemm_bt<1, 768, 64, 128, 2, 2, 2><<<64 * 6 * 2, 256, 0, stream>>>(
        AO, Wot, nullptr, nullptr, nullptr, pp, nullptr, nullptr, nullptr);
    merge_ln_kernel<true><<<M_, 256, 0, stream>>>(
        pp, bo, x, nullptr, gamma, beta, nullptr, x1b);

    // FFN1: 64x128 tiles -> 1536 blocks
    gemm_bt<2, 768, 64, 128, 2, 2, 1><<<64 * 24, 256, 0, stream>>>(
        x1b, W1t, b1, nullptr, nullptr, hbuf, nullptr, nullptr, nullptr);

    // FFN2: 64x128 tiles + K-split x2 -> 768 blocks; merge + bias + resid + LN2
    gemm_bt<3, 3072, 64, 128, 2, 2, 2><<<64 * 6 * 2, 256, 0, stream>>>(
        hbuf, W2t, nullptr, nullptr, nullptr, pp, nullptr, nullptr, nullptr);
    merge_ln_kernel<false><<<M_, 256, 0, stream>>>(
        pp, b2, nullptr, x1b, gamma, beta, (float*)d_out, nullptr);
}